// Round 4
// baseline (211.254 us; speedup 1.0000x reference)
//
#include <hip/hip_runtime.h>

// LJ constants (sigma=1, eps=1, cutoff=5)
// SHIFT = 4*((1/5)^12 - (1/5)^6)
__device__ __constant__ float kShift = 4.0f * (float)(1.0 / 244140625.0 - 1.0 / 15625.0);

#define GROUPS 3
#define MAX_MEMBERS 85             // 3*85 = 255 blocks -> 1 block/CU, one CU idle
#define BUCKET 33334               // atoms per group; 33334*4B = 133,336 B LDS (< 160 KiB/CU)
#define BLOCK_T 1024               // 16 waves

__device__ __forceinline__ float lj_half_e(float x, float y, float z) {
    float r2 = x * x + y * y + z * z;
    float inv_r2 = 1.0f / r2;
    float sr6 = inv_r2 * inv_r2 * inv_r2;   // (sigma/r)^6
    float sr12 = sr6 * sr6;
    float e = 4.0f * (sr12 - sr6) - kShift;
    return 0.5f * e;
}

// Gather: group g (of 3) owns atoms [g*BUCKET, (g+1)*BUCKET). Its `members`
// blocks partition all edges; endpoints in-range accumulate via LDS atomics
// (zero global atomics). Each block streams its bucket to ws[blockIdx].
__global__ __launch_bounds__(BLOCK_T) void lj_gather_group(
        const float* __restrict__ dist,
        const int* __restrict__ atom_a,
        const int* __restrict__ atom_b,
        float* __restrict__ ws,
        int members, int n_edges) {
    __shared__ float acc[BUCKET];

    const int g = blockIdx.x / members;
    const int m = blockIdx.x % members;
    const unsigned lo = (unsigned)(g * BUCKET);

    for (int i = threadIdx.x; i < BUCKET; i += BLOCK_T) acc[i] = 0.0f;
    __syncthreads();

    const long long quads = ((long long)n_edges + 3) / 4;
    const long long per = (quads + members - 1) / members;
    const long long q0 = (long long)m * per;
    const long long q1 = (q0 + per < quads) ? (q0 + per) : quads;

    for (long long q = q0 + threadIdx.x; q < q1; q += BLOCK_T) {
        long long e0 = q * 4;
        if (e0 + 3 < n_edges) {
            const float4* d4 = (const float4*)(dist) + (size_t)q * 3;
            float4 v0 = d4[0];
            float4 v1 = d4[1];
            float4 v2 = d4[2];
            int4 ia = ((const int4*)atom_a)[q];
            int4 ib = ((const int4*)atom_b)[q];

            float h0 = lj_half_e(v0.x, v0.y, v0.z);
            float h1 = lj_half_e(v0.w, v1.x, v1.y);
            float h2 = lj_half_e(v1.z, v1.w, v2.x);
            float h3 = lj_half_e(v2.y, v2.z, v2.w);

            unsigned r;
            r = (unsigned)ia.x - lo; if (r < BUCKET) atomicAdd(&acc[r], h0);
            r = (unsigned)ib.x - lo; if (r < BUCKET) atomicAdd(&acc[r], h0);
            r = (unsigned)ia.y - lo; if (r < BUCKET) atomicAdd(&acc[r], h1);
            r = (unsigned)ib.y - lo; if (r < BUCKET) atomicAdd(&acc[r], h1);
            r = (unsigned)ia.z - lo; if (r < BUCKET) atomicAdd(&acc[r], h2);
            r = (unsigned)ib.z - lo; if (r < BUCKET) atomicAdd(&acc[r], h2);
            r = (unsigned)ia.w - lo; if (r < BUCKET) atomicAdd(&acc[r], h3);
            r = (unsigned)ib.w - lo; if (r < BUCKET) atomicAdd(&acc[r], h3);
        } else {
            for (long long e = e0; e < n_edges; ++e) {
                float x = dist[e * 3 + 0];
                float y = dist[e * 3 + 1];
                float z = dist[e * 3 + 2];
                float h = lj_half_e(x, y, z);
                unsigned r;
                r = (unsigned)atom_a[e] - lo; if (r < BUCKET) atomicAdd(&acc[r], h);
                r = (unsigned)atom_b[e] - lo; if (r < BUCKET) atomicAdd(&acc[r], h);
            }
        }
    }
    __syncthreads();

    float* dst = ws + (size_t)blockIdx.x * BUCKET;
    for (int i = threadIdx.x; i < BUCKET; i += BLOCK_T) dst[i] = acc[i];
}

// out[a] = sum over the `members` partials of a's group.
__global__ void reduce_groups(const float* __restrict__ ws,
                              float* __restrict__ out,
                              int members, int n_atoms) {
    int i = blockIdx.x * blockDim.x + threadIdx.x;
    if (i >= n_atoms) return;
    int g = i / BUCKET;
    int off = i - g * BUCKET;
    const float* base = ws + ((size_t)g * members) * BUCKET + off;
    float s = 0.0f;
    for (int b = 0; b < members; ++b) s += base[(size_t)b * BUCKET];
    out[i] = s;
}

// Fallback (ws far too small): device-scope atomics straight into out. Slow but correct.
__global__ void lj_scatter_direct(const float* __restrict__ dist,
                                  const int* __restrict__ atom_a,
                                  const int* __restrict__ atom_b,
                                  float* __restrict__ out,
                                  int n_edges) {
    int t = blockIdx.x * blockDim.x + threadIdx.x;
    long long e0 = (long long)t * 4;
    if (e0 >= n_edges) return;
    if (e0 + 3 < n_edges) {
        const float4* d4 = (const float4*)(dist) + (size_t)t * 3;
        float4 v0 = d4[0];
        float4 v1 = d4[1];
        float4 v2 = d4[2];
        int4 ia = ((const int4*)atom_a)[t];
        int4 ib = ((const int4*)atom_b)[t];
        float h0 = lj_half_e(v0.x, v0.y, v0.z);
        float h1 = lj_half_e(v0.w, v1.x, v1.y);
        float h2 = lj_half_e(v1.z, v1.w, v2.x);
        float h3 = lj_half_e(v2.y, v2.z, v2.w);
        atomicAdd(&out[ia.x], h0);
        atomicAdd(&out[ib.x], h0);
        atomicAdd(&out[ia.y], h1);
        atomicAdd(&out[ib.y], h1);
        atomicAdd(&out[ia.z], h2);
        atomicAdd(&out[ib.z], h2);
        atomicAdd(&out[ia.w], h3);
        atomicAdd(&out[ib.w], h3);
    } else {
        for (long long e = e0; e < n_edges; ++e) {
            float x = dist[e * 3 + 0];
            float y = dist[e * 3 + 1];
            float z = dist[e * 3 + 2];
            float h = lj_half_e(x, y, z);
            atomicAdd(&out[atom_a[e]], h);
            atomicAdd(&out[atom_b[e]], h);
        }
    }
}

extern "C" void kernel_launch(void* const* d_in, const int* in_sizes, int n_in,
                              void* d_out, int out_size, void* d_ws, size_t ws_size,
                              hipStream_t stream) {
    const float* dist = (const float*)d_in[0];
    const int* atom_a = (const int*)d_in[1];
    const int* atom_b = (const int*)d_in[2];
    float* out = (float*)d_out;

    int n_edges = in_sizes[1];
    int n_atoms = out_size;

    // Size member count against available ws (partials = GROUPS*members*BUCKET*4B).
    size_t per_member = (size_t)GROUPS * BUCKET * sizeof(float);
    int members = (int)(ws_size / per_member);
    if (members > MAX_MEMBERS) members = MAX_MEMBERS;
    bool range_ok = ((long long)GROUPS * BUCKET >= (long long)n_atoms);

    if (members >= 8 && range_ok) {
        float* ws = (float*)d_ws;
        lj_gather_group<<<GROUPS * members, BLOCK_T, 0, stream>>>(
            dist, atom_a, atom_b, ws, members, n_edges);
        int rblock = 256;
        int rgrid = (n_atoms + rblock - 1) / rblock;
        reduce_groups<<<rgrid, rblock, 0, stream>>>(ws, out, members, n_atoms);
    } else {
        hipMemsetAsync(d_out, 0, (size_t)n_atoms * sizeof(float), stream);
        int n_quads = (n_edges + 3) / 4;
        int block = 256;
        int grid = (n_quads + block - 1) / block;
        lj_scatter_direct<<<grid, block, 0, stream>>>(dist, atom_a, atom_b, out, n_edges);
    }
}

// Round 5
// 201.326 us; speedup vs baseline: 1.0493x; 1.0493x over previous
//
#include <hip/hip_runtime.h>

// LJ constants (sigma=1, eps=1, cutoff=5)
// SHIFT = 4*((1/5)^12 - (1/5)^6)
__device__ __constant__ float kShift = 4.0f * (float)(1.0 / 244140625.0 - 1.0 / 15625.0);

#define GROUPS 3
#define SLICES 80                  // 3*80 = 240 blocks (1/CU, 16 CUs idle)
#define BUCKET 33334               // atoms per group; 133,336 B LDS
#define BLOCK_T 1024               // 16 waves

// XCD-alignment: blocks sharing slice s must land on the same XCD so the
// slice is fetched from HBM once and re-served from that XCD's 4 MiB L2.
// blockIdx = (s%8) + 8*(3*(s/8) + g)  =>  same-slice trio has identical
// blockIdx%8 (same XCD under round-robin dispatch) and differs by only 8
// (same XCD under chunked dispatch) — hedged against both mappings.

__device__ __forceinline__ float lj_half_e(float x, float y, float z) {
    float r2 = x * x + y * y + z * z;
    float inv_r2 = 1.0f / r2;
    float sr6 = inv_r2 * inv_r2 * inv_r2;   // (sigma/r)^6
    float sr12 = sr6 * sr6;
    float e = 4.0f * (sr12 - sr6) - kShift;
    return 0.5f * e;
}

__global__ __launch_bounds__(BLOCK_T) void lj_gather_group(
        const float* __restrict__ dist,
        const int* __restrict__ atom_a,
        const int* __restrict__ atom_b,
        float* __restrict__ ws,
        int n_edges) {
    __shared__ float acc[BUCKET];

    // Decode (group, slice) from the XCD-aligned block id.
    const int b = blockIdx.x;
    const int r = b & 7;
    const int t = b >> 3;
    const int g = t % GROUPS;
    const int k = t / GROUPS;
    const int s = (k << 3) + r;            // slice in [0, SLICES)
    const unsigned lo = (unsigned)(g * BUCKET);

    for (int i = threadIdx.x; i < BUCKET; i += BLOCK_T) acc[i] = 0.0f;
    __syncthreads();

    const long long quads = (long long)n_edges >> 2;
    const long long per = (quads + SLICES - 1) / SLICES;
    const long long q0 = (long long)s * per;
    const long long qe = (q0 + per < quads) ? (q0 + per) : quads;

    // 2 quads per thread per iteration: all loads issued before any LDS
    // atomic so two full load-bundles are in flight per wave.
    for (long long base = q0; base < qe; base += 2 * BLOCK_T) {
        long long qa = base + threadIdx.x;
        long long qb = qa + BLOCK_T;
        bool vA = (qa < qe);
        bool vB = (qb < qe);

        float4 A0, A1, A2, B0, B1, B2;
        int4 IAa, IBa, IAb, IBb;
        if (vA) {
            const float4* d4 = (const float4*)(dist) + (size_t)qa * 3;
            A0 = d4[0]; A1 = d4[1]; A2 = d4[2];
            IAa = ((const int4*)atom_a)[qa];
            IBa = ((const int4*)atom_b)[qa];
        }
        if (vB) {
            const float4* d4 = (const float4*)(dist) + (size_t)qb * 3;
            B0 = d4[0]; B1 = d4[1]; B2 = d4[2];
            IAb = ((const int4*)atom_a)[qb];
            IBb = ((const int4*)atom_b)[qb];
        }

        if (vA) {
            float h0 = lj_half_e(A0.x, A0.y, A0.z);
            float h1 = lj_half_e(A0.w, A1.x, A1.y);
            float h2 = lj_half_e(A1.z, A1.w, A2.x);
            float h3 = lj_half_e(A2.y, A2.z, A2.w);
            unsigned u;
            u = (unsigned)IAa.x - lo; if (u < BUCKET) atomicAdd(&acc[u], h0);
            u = (unsigned)IBa.x - lo; if (u < BUCKET) atomicAdd(&acc[u], h0);
            u = (unsigned)IAa.y - lo; if (u < BUCKET) atomicAdd(&acc[u], h1);
            u = (unsigned)IBa.y - lo; if (u < BUCKET) atomicAdd(&acc[u], h1);
            u = (unsigned)IAa.z - lo; if (u < BUCKET) atomicAdd(&acc[u], h2);
            u = (unsigned)IBa.z - lo; if (u < BUCKET) atomicAdd(&acc[u], h2);
            u = (unsigned)IAa.w - lo; if (u < BUCKET) atomicAdd(&acc[u], h3);
            u = (unsigned)IBa.w - lo; if (u < BUCKET) atomicAdd(&acc[u], h3);
        }
        if (vB) {
            float h0 = lj_half_e(B0.x, B0.y, B0.z);
            float h1 = lj_half_e(B0.w, B1.x, B1.y);
            float h2 = lj_half_e(B1.z, B1.w, B2.x);
            float h3 = lj_half_e(B2.y, B2.z, B2.w);
            unsigned u;
            u = (unsigned)IAb.x - lo; if (u < BUCKET) atomicAdd(&acc[u], h0);
            u = (unsigned)IBb.x - lo; if (u < BUCKET) atomicAdd(&acc[u], h0);
            u = (unsigned)IAb.y - lo; if (u < BUCKET) atomicAdd(&acc[u], h1);
            u = (unsigned)IBb.y - lo; if (u < BUCKET) atomicAdd(&acc[u], h1);
            u = (unsigned)IAb.z - lo; if (u < BUCKET) atomicAdd(&acc[u], h2);
            u = (unsigned)IBb.z - lo; if (u < BUCKET) atomicAdd(&acc[u], h2);
            u = (unsigned)IAb.w - lo; if (u < BUCKET) atomicAdd(&acc[u], h3);
            u = (unsigned)IBb.w - lo; if (u < BUCKET) atomicAdd(&acc[u], h3);
        }
    }

    // Edge-count tail (n_edges % 4 != 0) — handled by last slice's blocks.
    if ((n_edges & 3) && s == SLICES - 1) {
        for (long long e = quads * 4 + threadIdx.x; e < n_edges; e += BLOCK_T) {
            float x = dist[e * 3 + 0];
            float y = dist[e * 3 + 1];
            float z = dist[e * 3 + 2];
            float h = lj_half_e(x, y, z);
            unsigned u;
            u = (unsigned)atom_a[e] - lo; if (u < BUCKET) atomicAdd(&acc[u], h);
            u = (unsigned)atom_b[e] - lo; if (u < BUCKET) atomicAdd(&acc[u], h);
        }
    }
    __syncthreads();

    // Partials laid out by (g, s) so the reduce is dense per group.
    float* dst = ws + ((size_t)(g * SLICES + s)) * BUCKET;
    for (int i = threadIdx.x; i < BUCKET; i += BLOCK_T) dst[i] = acc[i];
}

// out[a] = sum over the SLICES partials of a's group.
__global__ void reduce_groups(const float* __restrict__ ws,
                              float* __restrict__ out,
                              int n_atoms) {
    int i = blockIdx.x * blockDim.x + threadIdx.x;
    if (i >= n_atoms) return;
    int g = i / BUCKET;
    int off = i - g * BUCKET;
    const float* base = ws + ((size_t)g * SLICES) * BUCKET + off;
    float s = 0.0f;
    #pragma unroll 8
    for (int b = 0; b < SLICES; ++b) s += base[(size_t)b * BUCKET];
    out[i] = s;
}

// Fallback (ws too small): device-scope atomics straight into out. Slow but correct.
__global__ void lj_scatter_direct(const float* __restrict__ dist,
                                  const int* __restrict__ atom_a,
                                  const int* __restrict__ atom_b,
                                  float* __restrict__ out,
                                  int n_edges) {
    int t = blockIdx.x * blockDim.x + threadIdx.x;
    long long e0 = (long long)t * 4;
    if (e0 >= n_edges) return;
    if (e0 + 3 < n_edges) {
        const float4* d4 = (const float4*)(dist) + (size_t)t * 3;
        float4 v0 = d4[0];
        float4 v1 = d4[1];
        float4 v2 = d4[2];
        int4 ia = ((const int4*)atom_a)[t];
        int4 ib = ((const int4*)atom_b)[t];
        float h0 = lj_half_e(v0.x, v0.y, v0.z);
        float h1 = lj_half_e(v0.w, v1.x, v1.y);
        float h2 = lj_half_e(v1.z, v1.w, v2.x);
        float h3 = lj_half_e(v2.y, v2.z, v2.w);
        atomicAdd(&out[ia.x], h0);
        atomicAdd(&out[ib.x], h0);
        atomicAdd(&out[ia.y], h1);
        atomicAdd(&out[ib.y], h1);
        atomicAdd(&out[ia.z], h2);
        atomicAdd(&out[ib.z], h2);
        atomicAdd(&out[ia.w], h3);
        atomicAdd(&out[ib.w], h3);
    } else {
        for (long long e = e0; e < n_edges; ++e) {
            float x = dist[e * 3 + 0];
            float y = dist[e * 3 + 1];
            float z = dist[e * 3 + 2];
            float h = lj_half_e(x, y, z);
            atomicAdd(&out[atom_a[e]], h);
            atomicAdd(&out[atom_b[e]], h);
        }
    }
}

extern "C" void kernel_launch(void* const* d_in, const int* in_sizes, int n_in,
                              void* d_out, int out_size, void* d_ws, size_t ws_size,
                              hipStream_t stream) {
    const float* dist = (const float*)d_in[0];
    const int* atom_a = (const int*)d_in[1];
    const int* atom_b = (const int*)d_in[2];
    float* out = (float*)d_out;

    int n_edges = in_sizes[1];
    int n_atoms = out_size;

    size_t need = (size_t)GROUPS * SLICES * BUCKET * sizeof(float);  // ~32 MB
    bool range_ok = ((long long)GROUPS * BUCKET >= (long long)n_atoms);

    if (ws_size >= need && range_ok) {
        float* ws = (float*)d_ws;
        lj_gather_group<<<GROUPS * SLICES, BLOCK_T, 0, stream>>>(
            dist, atom_a, atom_b, ws, n_edges);
        int rblock = 256;
        int rgrid = (n_atoms + rblock - 1) / rblock;
        reduce_groups<<<rgrid, rblock, 0, stream>>>(ws, out, n_atoms);
    } else {
        hipMemsetAsync(d_out, 0, (size_t)n_atoms * sizeof(float), stream);
        int n_quads = (n_edges + 3) / 4;
        int block = 256;
        int grid = (n_quads + block - 1) / block;
        lj_scatter_direct<<<grid, block, 0, stream>>>(dist, atom_a, atom_b, out, n_edges);
    }
}